// Round 11
// baseline (26.327 us; speedup 1.0000x reference)
//
#include <hip/hip_runtime.h>
#include <hip/hip_bf16.h>

// TrajectoryInformedSplatAttention — R9 (DPP reduce) + non-temporal stores.
// B=4, S=4096, D=1024, maxd=8.
//
// traj[b,s,:] = sum_{jr=0..8} g[s][jr] * emb[b, s-8+jr, :]   (telescoped)
//   g[jr] = (c[jr-1]-c[jr])/wsum, c[j] = lin(s,j)*q[i], i=s-8+j
//   q = tanh(2*mag)/mag (0 if mag<=1e-6), wsum = max(sum lin*tanh(2*mag),1e-8)
//
// vs R9: output stores are non-temporal — the output stream is never re-read,
// so don't let it allocate in L2/L3 and evict the input (which IS re-read
// every graph replay; R7 showed FETCH 37MB < 64MB input = partial L3
// residency). R10 fix: the builtin needs a BUILTIN vector type, not HIP's
// float2 class -> ext_vector_type(2) alias.

constexpr int B_ = 4;
constexpr int S_ = 4096;
constexpr int D_ = 1024;
constexpr int MAXD  = 8;
constexpr int CHUNK = 32;
constexpr int ROWS  = CHUNK + MAXD;      // 40-row register window
constexpr int NDIFF = ROWS - 1;          // 39 adjacent diffs
constexpr int NCH   = S_ / CHUNK;        // 128 s-chunks
constexpr int NWG   = B_ * NCH;          // 512 blocks
constexpr int NXCD  = 8;

typedef float fx2 __attribute__((ext_vector_type(2)));

// x += dpp_shifted(x); old=0 so shifted-in / unmasked rows contribute 0.
template <int CTRL, int ROW_MASK>
__device__ __forceinline__ float dpp_add(float x) {
    const int t = __builtin_amdgcn_update_dpp(0, __float_as_int(x),
                                              CTRL, ROW_MASK, 0xf, false);
    return x + __int_as_float(t);
}

// Full 64-lane sum -> lane 63. row_shr:N = 0x110|N, bcast15=0x142, bcast31=0x143.
__device__ __forceinline__ float wave_reduce_dpp(float x) {
    x = dpp_add<0x111, 0xf>(x);   // += lane-1
    x = dpp_add<0x112, 0xf>(x);   // += lane-2
    x = dpp_add<0x114, 0xf>(x);   // += lane-4
    x = dpp_add<0x118, 0xf>(x);   // += lane-8   -> lane 15+16k = row sums
    x = dpp_add<0x142, 0xa>(x);   // rows 1,3 += bcast(lane15/47)
    x = dpp_add<0x143, 0xc>(x);   // rows 2,3 += bcast(lane31)   -> lane63 total
    return x;
}

__global__ __launch_bounds__(512, 4)
void traj_splat_kernel(const float* __restrict__ emb, float* __restrict__ out) {
    // XCD swizzle (NWG % 8 == 0 -> bijective): consecutive lin on one XCD are
    // consecutive s-chunks -> 8-row halo is an L2 hit.
    const int bid = blockIdx.x;
    const int lin = (bid % NXCD) * (NWG / NXCD) + bid / NXCD;
    const int schunk = lin & (NCH - 1);
    const int b      = lin >> 7;

    const int s0   = schunk * CHUNK;
    const int lane = threadIdx.x & 63;
    const int wave = threadIdx.x >> 6;    // 8 waves
    const int d0   = threadIdx.x * 2;     // 512 threads * 2 floats = 1024 = D

    const float* __restrict__ embB = emb + (size_t)b * S_ * D_;

    __shared__ float part[NDIFF][9];      // 8 wave-sums/diff + 1 pad
    __shared__ float smagw[NDIFF];
    __shared__ float sq[NDIFF];
    __shared__ float gco[CHUNK][12];

    // ---- Phase A: 40-row window, float2/thread (independent loads, ILP) ----
    float2 win[ROWS];
    #pragma unroll
    for (int r = 0; r < ROWS; ++r) {
        const int row = s0 - MAXD + r;    // max = s0+31 <= S-1
        win[r] = (row >= 0) ? *(const float2*)(embB + (size_t)row * D_ + d0)
                            : make_float2(0.f, 0.f);
    }

    // ---- Phase B: 39 full-D diff magnitudes via DPP (VALU-only reduce) ----
    #pragma unroll
    for (int li = 0; li < NDIFF; ++li) {
        const float2 a = win[li], c = win[li + 1];
        const float dx = c.x - a.x, dy = c.y - a.y;
        float sum = dx * dx + dy * dy;
        sum = wave_reduce_dpp(sum);
        if (lane == 63) part[li][wave] = sum;
    }
    __syncthreads();

    if (threadIdx.x < NDIFF) {
        const int li = threadIdx.x;
        float s2 = 0.f;
        #pragma unroll
        for (int k = 0; k < 8; ++k) s2 += part[li][k];
        const float mag = sqrtf(s2);                     // FULL-D magnitude
        const float mw  = tanhf(2.f * mag);
        smagw[li] = mw;
        sq[li]    = (mag > 1e-6f) ? (mw / mag) : 0.f;
    }
    __syncthreads();

    // ---- Phase C1: CHUNK threads build the 9 telescoped coefficients per s ----
    if (threadIdx.x < CHUNK) {
        const int sl = threadIdx.x;
        const int s  = s0 + sl;
        const int ws = min(MAXD, s);
        const int lo = MAXD - ws;
        const float rden = 0.9f / (float)max(ws - 1, 1);

        float cpad[MAXD + 2];
        #pragma unroll
        for (int t = 0; t < MAXD + 2; ++t) cpad[t] = 0.f;

        float wsum = 0.f;
        #pragma unroll
        for (int j = 0; j < MAXD; ++j) {
            if (j >= lo) {
                const int li = sl + j;               // diff at global index s-8+j
                const float lin2 = (ws > 1) ? (0.1f + rden * (float)(j - lo)) : 0.1f;
                wsum += lin2 * smagw[li];
                cpad[j + 1] = lin2 * sq[li];
            }
        }
        const float inv = 1.f / fmaxf(wsum, 1e-8f);
        #pragma unroll
        for (int jr = 0; jr <= MAXD; ++jr)
            gco[sl][jr] = (cpad[jr] - cpad[jr + 1]) * inv;
    }
    __syncthreads();

    // ---- Phase C2: outputs from registers; non-temporal (streaming) stores ----
    float* outB = out + ((size_t)b * S_ + s0) * D_ + d0;
    #pragma unroll
    for (int sl = 0; sl < CHUNK; ++sl) {
        const float4 g0 = *(const float4*)&gco[sl][0];   // g[0..3] (broadcast)
        const float4 g1 = *(const float4*)&gco[sl][4];   // g[4..7]
        const float  g8 = gco[sl][8];

        float ax = g0.x * win[sl].x;
        float ay = g0.x * win[sl].y;
        const float gs[8] = {g0.y, g0.z, g0.w, g1.x, g1.y, g1.z, g1.w, g8};
        #pragma unroll
        for (int jr = 1; jr <= MAXD; ++jr) {
            const float g = gs[jr - 1];
            ax += g * win[sl + jr].x;
            ay += g * win[sl + jr].y;
        }
        fx2 acc2; acc2.x = ax; acc2.y = ay;
        __builtin_nontemporal_store(acc2, (fx2*)(outB + (size_t)sl * D_));
    }
}

extern "C" void kernel_launch(void* const* d_in, const int* in_sizes, int n_in,
                              void* d_out, int out_size, void* d_ws, size_t ws_size,
                              hipStream_t stream) {
    const float* emb = (const float*)d_in[0];
    float* out = (float*)d_out;

    dim3 grid(NWG);      // 512 blocks, swizzled in-kernel
    dim3 block(512);
    traj_splat_kernel<<<grid, block, 0, stream>>>(emb, out);
}

// Round 12
// 25.927 us; speedup vs baseline: 1.0154x; 1.0154x over previous
//
#include <hip/hip_runtime.h>
#include <hip/hip_bf16.h>

// TrajectoryInformedSplatAttention — float4 loads + DPP reduce + NT stores.
// B=4, S=4096, D=1024, maxd=8.
//
// traj[b,s,:] = sum_{jr=0..8} g[s][jr] * emb[b, s-8+jr, :]   (telescoped)
//   g[jr] = (c[jr-1]-c[jr])/wsum, c[j] = lin(s,j)*q[i], i=s-8+j
//   q = tanh(2*mag)/mag (0 if mag<=1e-6), wsum = max(sum lin*tanh(2*mag),1e-8)
//
// vs R11: back to 256 threads x float4 (16 B/lane = coalescing sweet spot,
// half the load instructions of the float2/512 variant) while keeping the
// DPP wave reduction and non-temporal stores. Decision probe: neutral result
// here means the mixed read+write stream ceiling is the structural limit.

constexpr int B_ = 4;
constexpr int S_ = 4096;
constexpr int D_ = 1024;
constexpr int MAXD  = 8;
constexpr int CHUNK = 32;
constexpr int ROWS  = CHUNK + MAXD;      // 40-row register window
constexpr int NDIFF = ROWS - 1;          // 39 adjacent diffs
constexpr int NCH   = S_ / CHUNK;        // 128 s-chunks
constexpr int NWG   = B_ * NCH;          // 512 blocks
constexpr int NXCD  = 8;

typedef float fx4 __attribute__((ext_vector_type(4)));

// x += dpp_shifted(x); old=0 so shifted-in / unmasked rows contribute 0.
template <int CTRL, int ROW_MASK>
__device__ __forceinline__ float dpp_add(float x) {
    const int t = __builtin_amdgcn_update_dpp(0, __float_as_int(x),
                                              CTRL, ROW_MASK, 0xf, false);
    return x + __int_as_float(t);
}

// Full 64-lane sum -> lane 63. row_shr:N = 0x110|N, bcast15=0x142, bcast31=0x143.
__device__ __forceinline__ float wave_reduce_dpp(float x) {
    x = dpp_add<0x111, 0xf>(x);   // += lane-1
    x = dpp_add<0x112, 0xf>(x);   // += lane-2
    x = dpp_add<0x114, 0xf>(x);   // += lane-4
    x = dpp_add<0x118, 0xf>(x);   // += lane-8   -> lane 15+16k = row sums
    x = dpp_add<0x142, 0xa>(x);   // rows 1,3 += bcast(lane15/47)
    x = dpp_add<0x143, 0xc>(x);   // rows 2,3 += bcast(lane31)   -> lane63 total
    return x;
}

__global__ __launch_bounds__(256, 2)
void traj_splat_kernel(const float* __restrict__ emb, float* __restrict__ out) {
    // XCD swizzle (NWG % 8 == 0 -> bijective): consecutive lin on one XCD are
    // consecutive s-chunks -> 8-row halo is an L2 hit.
    const int bid = blockIdx.x;
    const int lin = (bid % NXCD) * (NWG / NXCD) + bid / NXCD;
    const int schunk = lin & (NCH - 1);
    const int b      = lin >> 7;

    const int s0   = schunk * CHUNK;
    const int lane = threadIdx.x & 63;
    const int wave = threadIdx.x >> 6;    // 4 waves
    const int d0   = threadIdx.x * 4;     // 256 threads * 4 floats = 1024 = D

    const float* __restrict__ embB = emb + (size_t)b * S_ * D_;

    __shared__ float part[NDIFF][5];      // 4 wave-sums/diff + 1 pad
    __shared__ float smagw[NDIFF];
    __shared__ float sq[NDIFF];
    __shared__ float gco[CHUNK][12];

    // ---- Phase A: 40-row window, float4/thread (1 KiB per load inst) ----
    float4 win[ROWS];
    #pragma unroll
    for (int r = 0; r < ROWS; ++r) {
        const int row = s0 - MAXD + r;    // max = s0+31 <= S-1
        win[r] = (row >= 0) ? *(const float4*)(embB + (size_t)row * D_ + d0)
                            : make_float4(0.f, 0.f, 0.f, 0.f);
    }

    // ---- Phase B: 39 full-D diff magnitudes via DPP (VALU-only reduce) ----
    #pragma unroll
    for (int li = 0; li < NDIFF; ++li) {
        const float4 a = win[li], c = win[li + 1];
        const float dx = c.x - a.x, dy = c.y - a.y;
        const float dz = c.z - a.z, dw = c.w - a.w;
        float sum = dx * dx + dy * dy + dz * dz + dw * dw;
        sum = wave_reduce_dpp(sum);
        if (lane == 63) part[li][wave] = sum;
    }
    __syncthreads();

    if (threadIdx.x < NDIFF) {
        const int li = threadIdx.x;
        const float s2 = part[li][0] + part[li][1] + part[li][2] + part[li][3];
        const float mag = sqrtf(s2);                     // FULL-D magnitude
        const float mw  = tanhf(2.f * mag);
        smagw[li] = mw;
        sq[li]    = (mag > 1e-6f) ? (mw / mag) : 0.f;
    }
    __syncthreads();

    // ---- Phase C1: CHUNK threads build the 9 telescoped coefficients per s ----
    if (threadIdx.x < CHUNK) {
        const int sl = threadIdx.x;
        const int s  = s0 + sl;
        const int ws = min(MAXD, s);
        const int lo = MAXD - ws;
        const float rden = 0.9f / (float)max(ws - 1, 1);

        float cpad[MAXD + 2];
        #pragma unroll
        for (int t = 0; t < MAXD + 2; ++t) cpad[t] = 0.f;

        float wsum = 0.f;
        #pragma unroll
        for (int j = 0; j < MAXD; ++j) {
            if (j >= lo) {
                const int li = sl + j;               // diff at global index s-8+j
                const float lin2 = (ws > 1) ? (0.1f + rden * (float)(j - lo)) : 0.1f;
                wsum += lin2 * smagw[li];
                cpad[j + 1] = lin2 * sq[li];
            }
        }
        const float inv = 1.f / fmaxf(wsum, 1e-8f);
        #pragma unroll
        for (int jr = 0; jr <= MAXD; ++jr)
            gco[sl][jr] = (cpad[jr] - cpad[jr + 1]) * inv;
    }
    __syncthreads();

    // ---- Phase C2: outputs from registers; non-temporal 16 B stores ----
    float* outB = out + ((size_t)b * S_ + s0) * D_ + d0;
    #pragma unroll
    for (int sl = 0; sl < CHUNK; ++sl) {
        const float4 g0 = *(const float4*)&gco[sl][0];   // g[0..3] (broadcast)
        const float4 g1 = *(const float4*)&gco[sl][4];   // g[4..7]
        const float  g8 = gco[sl][8];

        float ax = g0.x * win[sl].x;
        float ay = g0.x * win[sl].y;
        float az = g0.x * win[sl].z;
        float aw = g0.x * win[sl].w;
        const float gs[8] = {g0.y, g0.z, g0.w, g1.x, g1.y, g1.z, g1.w, g8};
        #pragma unroll
        for (int jr = 1; jr <= MAXD; ++jr) {
            const float g = gs[jr - 1];
            ax += g * win[sl + jr].x;
            ay += g * win[sl + jr].y;
            az += g * win[sl + jr].z;
            aw += g * win[sl + jr].w;
        }
        fx4 acc4; acc4.x = ax; acc4.y = ay; acc4.z = az; acc4.w = aw;
        __builtin_nontemporal_store(acc4, (fx4*)(outB + (size_t)sl * D_));
    }
}

extern "C" void kernel_launch(void* const* d_in, const int* in_sizes, int n_in,
                              void* d_out, int out_size, void* d_ws, size_t ws_size,
                              hipStream_t stream) {
    const float* emb = (const float*)d_in[0];
    float* out = (float*)d_out;

    dim3 grid(NWG);      // 512 blocks, swizzled in-kernel
    dim3 block(256);
    traj_splat_kernel<<<grid, block, 0, stream>>>(emb, out);
}